// Round 1
// baseline (1073.351 us; speedup 1.0000x reference)
//
#include <hip/hip_runtime.h>
#include <hip/hip_bf16.h>

#define NN 100000
#define EE 1200000
#define F1 128
#define F2 256
#define F3 40
#define ROWS 16

// ---------------- degree / norm ----------------
__global__ void k_deg_init(float* __restrict__ deg) {
    int i = blockIdx.x * blockDim.x + threadIdx.x;
    if (i < NN) deg[i] = 1.0f;   // self-loop
}

__global__ void k_deg_count(const int* __restrict__ col, float* __restrict__ deg) {
    int e = blockIdx.x * blockDim.x + threadIdx.x;
    if (e < EE) {
        int c = col[e];
        if ((unsigned)c < (unsigned)NN) atomicAdd(&deg[c], 1.0f);
    }
}

__global__ void k_dinv(float* __restrict__ deg) {
    int i = blockIdx.x * blockDim.x + threadIdx.x;
    if (i < NN) deg[i] = rsqrtf(deg[i]);   // deg >= 1 always
}

// ---------------- layer-1 aggregation of x (128-wide) ----------------
// agg[i] = x[i] * dinv[i]^2   (self-loop contribution, also zero-inits)
__global__ void k_agg_init(const float4* __restrict__ x, const float* __restrict__ dinv,
                           float4* __restrict__ agg) {
    int idx = blockIdx.x * blockDim.x + threadIdx.x;   // N*32 float4s
    if (idx < NN * 32) {
        int i = idx >> 5;
        float d = dinv[i];
        float w = d * d;
        float4 v = x[idx];
        v.x *= w; v.y *= w; v.z *= w; v.w *= w;
        agg[idx] = v;
    }
}

// one 64-lane wave per edge, 2 floats/lane
__global__ void k_scatter1(const int* __restrict__ row, const int* __restrict__ col,
                           const float* __restrict__ dinv, const float* __restrict__ x,
                           float* __restrict__ agg) {
    int lane = threadIdx.x & 63;
    int e = blockIdx.x * 4 + (threadIdx.x >> 6);
    if (e >= EE) return;
    int r = row[e], c = col[e];
    if ((unsigned)r >= (unsigned)NN || (unsigned)c >= (unsigned)NN) return;
    float w = dinv[r] * dinv[c];
    const float* xs = x + (size_t)r * F1;
    float* ag = agg + (size_t)c * F1;
    atomicAdd(&ag[lane],      xs[lane]      * w);
    atomicAdd(&ag[lane + 64], xs[lane + 64] * w);
}

// ---------------- fused GEMM1 + ReLU + GEMM2 ----------------
// h1 = relu(agg @ W1 + b1) kept in LDS; t = h1 @ W2 written to global.
__global__ __launch_bounds__(256) void k_gemm_fused(
    const float* __restrict__ agg, const float* __restrict__ W1,
    const float* __restrict__ b1, const float* __restrict__ W2,
    float* __restrict__ t) {
    __shared__ float a_s[ROWS * F1];   // 8 KB
    __shared__ float h_s[ROWS * F2];   // 16 KB
    const int i0 = blockIdx.x * ROWS;
    const int tid = threadIdx.x;

    // stage agg rows into LDS
    for (int o = tid; o < ROWS * F1; o += 256) {
        int r = o >> 7, k = o & (F1 - 1);
        int i = i0 + r;
        a_s[o] = (i < NN) ? agg[(size_t)i * F1 + k] : 0.0f;
    }
    __syncthreads();

    // h = relu(a @ W1 + b1): thread = column j, 16 rows each
    {
        const int j = tid;
        float acc[ROWS];
        float bj = b1[j];
#pragma unroll
        for (int r = 0; r < ROWS; ++r) acc[r] = bj;
        for (int k4 = 0; k4 < F1; k4 += 4) {
            float w0 = W1[(k4 + 0) * F2 + j];
            float w1 = W1[(k4 + 1) * F2 + j];
            float w2 = W1[(k4 + 2) * F2 + j];
            float w3 = W1[(k4 + 3) * F2 + j];
#pragma unroll
            for (int r = 0; r < ROWS; ++r) {
                float4 av = *(const float4*)&a_s[r * F1 + k4];
                acc[r] = fmaf(av.x, w0, acc[r]);
                acc[r] = fmaf(av.y, w1, acc[r]);
                acc[r] = fmaf(av.z, w2, acc[r]);
                acc[r] = fmaf(av.w, w3, acc[r]);
            }
        }
#pragma unroll
        for (int r = 0; r < ROWS; ++r) h_s[r * F2 + j] = fmaxf(acc[r], 0.0f);
    }
    __syncthreads();

    // t = h @ W2 : 16 rows x 40 cols = 640 outputs
    for (int o = tid; o < ROWS * F3; o += 256) {
        int r = o / F3, j2 = o - r * F3;
        float s = 0.0f;
        for (int k4 = 0; k4 < F2; k4 += 4) {
            float4 hv = *(const float4*)&h_s[r * F2 + k4];
            s = fmaf(hv.x, W2[(k4 + 0) * F3 + j2], s);
            s = fmaf(hv.y, W2[(k4 + 1) * F3 + j2], s);
            s = fmaf(hv.z, W2[(k4 + 2) * F3 + j2], s);
            s = fmaf(hv.w, W2[(k4 + 3) * F3 + j2], s);
        }
        int i = i0 + r;
        if (i < NN) t[(size_t)i * F3 + j2] = s;
    }
}

// ---------------- layer-2 aggregation (40-wide) ----------------
__global__ void k_out_init(const float* __restrict__ t, const float* __restrict__ dinv,
                           const float* __restrict__ b2, float* __restrict__ out) {
    int idx = blockIdx.x * blockDim.x + threadIdx.x;
    if (idx < NN * F3) {
        unsigned u = (unsigned)idx;
        unsigned i = u / F3;
        unsigned j = u - i * F3;
        float d = dinv[i];
        out[idx] = t[idx] * d * d + b2[j];
    }
}

__global__ void k_scatter2(const int* __restrict__ row, const int* __restrict__ col,
                           const float* __restrict__ dinv, const float* __restrict__ t,
                           float* __restrict__ out) {
    int lane = threadIdx.x & 63;
    int e = blockIdx.x * 4 + (threadIdx.x >> 6);
    if (e >= EE || lane >= F3) return;
    int r = row[e], c = col[e];
    if ((unsigned)r >= (unsigned)NN || (unsigned)c >= (unsigned)NN) return;
    float w = dinv[r] * dinv[c];
    atomicAdd(&out[(size_t)c * F3 + lane], t[(size_t)r * F3 + lane] * w);
}

extern "C" void kernel_launch(void* const* d_in, const int* in_sizes, int n_in,
                              void* d_out, int out_size, void* d_ws, size_t ws_size,
                              hipStream_t stream) {
    const float* x  = (const float*)d_in[0];
    const int*   ei = (const int*)d_in[1];      // [2, E] int32 (harness converts integers)
    const float* W1 = (const float*)d_in[2];
    const float* b1 = (const float*)d_in[3];
    const float* W2 = (const float*)d_in[4];
    const float* b2 = (const float*)d_in[5];
    float* out = (float*)d_out;

    const int* row = ei;
    const int* col = ei + EE;

    // workspace layout (all fp32): deg/dinv [N] | agg1 [N*128] | t [N*40]
    float* deg = (float*)d_ws;
    float* agg = deg + NN;            // byte offset 400000, 16B-aligned
    float* t   = agg + (size_t)NN * F1;

    k_deg_init <<<(NN + 255) / 256, 256, 0, stream>>>(deg);
    k_deg_count<<<(EE + 255) / 256, 256, 0, stream>>>(col, deg);
    k_dinv     <<<(NN + 255) / 256, 256, 0, stream>>>(deg);

    k_agg_init <<<(NN * 32 + 255) / 256, 256, 0, stream>>>((const float4*)x, deg, (float4*)agg);
    k_scatter1 <<<(EE + 3) / 4, 256, 0, stream>>>(row, col, deg, x, agg);

    k_gemm_fused<<<(NN + ROWS - 1) / ROWS, 256, 0, stream>>>(agg, W1, b1, W2, t);

    k_out_init <<<(NN * F3 + 255) / 256, 256, 0, stream>>>(t, deg, b2, out);
    k_scatter2 <<<(EE + 3) / 4, 256, 0, stream>>>(row, col, deg, t, out);
}

// Round 2
// 604.214 us; speedup vs baseline: 1.7764x; 1.7764x over previous
//
#include <hip/hip_runtime.h>
#include <hip/hip_bf16.h>

#define NN 100000
#define EE 1200000
#define F1 128
#define F2 256
#define F3 40
#define ROWS 16
#define NB ((NN + 255) / 256)   // 391 scan blocks

// ---------------- CSR build ----------------
__global__ void k_zero(int* __restrict__ cnt) {
    int i = blockIdx.x * blockDim.x + threadIdx.x;
    if (i < NN) cnt[i] = 0;
}

__global__ void k_count(const int* __restrict__ col, int* __restrict__ cnt) {
    int e = blockIdx.x * blockDim.x + threadIdx.x;
    if (e < EE) {
        int c = col[e];
        if ((unsigned)c < (unsigned)NN) atomicAdd(&cnt[c], 1);
    }
}

__global__ void k_dinv(const int* __restrict__ cnt, float* __restrict__ dinv) {
    int i = blockIdx.x * blockDim.x + threadIdx.x;
    if (i < NN) dinv[i] = rsqrtf((float)(cnt[i] + 1));   // +1 self-loop
}

// block-level exclusive scan of cnt -> cursor; per-block totals -> bsum
__global__ __launch_bounds__(256) void k_scan1(const int* __restrict__ cnt,
                                               int* __restrict__ cursor,
                                               int* __restrict__ bsum) {
    __shared__ int s[256];
    int g = blockIdx.x * 256 + threadIdx.x;
    int v = (g < NN) ? cnt[g] : 0;
    s[threadIdx.x] = v;
    __syncthreads();
    int acc = v;
    for (int d = 1; d < 256; d <<= 1) {
        int add = (threadIdx.x >= d) ? s[threadIdx.x - d] : 0;
        __syncthreads();
        acc += add;
        s[threadIdx.x] = acc;
        __syncthreads();
    }
    if (g < NN) cursor[g] = acc - v;          // exclusive within block
    if (threadIdx.x == 255) bsum[blockIdx.x] = acc;
}

// single-block exclusive scan of bsum (NB <= 512)
__global__ __launch_bounds__(512) void k_scan2(int* __restrict__ bsum) {
    __shared__ int s[512];
    int v = (threadIdx.x < NB) ? bsum[threadIdx.x] : 0;
    s[threadIdx.x] = v;
    __syncthreads();
    int acc = v;
    for (int d = 1; d < 512; d <<= 1) {
        int add = (threadIdx.x >= d) ? s[threadIdx.x - d] : 0;
        __syncthreads();
        acc += add;
        s[threadIdx.x] = acc;
        __syncthreads();
    }
    if (threadIdx.x < NB) bsum[threadIdx.x] = acc - v;
}

__global__ void k_scan3(int* __restrict__ cursor, const int* __restrict__ bsum) {
    int g = blockIdx.x * 256 + threadIdx.x;
    if (g < NN) cursor[g] += bsum[blockIdx.x];
}

// bucket source indices by destination; cursor[i] ends at off[i]+cnt[i]
__global__ void k_fill(const int* __restrict__ row, const int* __restrict__ col,
                       int* __restrict__ cursor, int* __restrict__ eidx) {
    int e = blockIdx.x * blockDim.x + threadIdx.x;
    if (e < EE) {
        int r = row[e], c = col[e];
        if ((unsigned)r < (unsigned)NN && (unsigned)c < (unsigned)NN) {
            int pos = atomicAdd(&cursor[c], 1);
            eidx[pos] = r;
        }
    }
}

// ---------------- layer-1 pull aggregation (128-wide, bf16 out) ----------------
// one wave per node: agg[i] = x[i]*dinv[i]^2 + sum_e x[r]*dinv[r]*dinv[i]
__global__ __launch_bounds__(256) void k_agg1(const int* __restrict__ cursor,
                                              const int* __restrict__ cnt,
                                              const int* __restrict__ eidx,
                                              const float* __restrict__ dinv,
                                              const float* __restrict__ x,
                                              __hip_bfloat16* __restrict__ agg) {
    int wave = blockIdx.x * 4 + (threadIdx.x >> 6);
    int lane = threadIdx.x & 63;
    if (wave >= NN) return;
    const int i = wave;
    float d = dinv[i];
    const float* xi = x + (size_t)i * F1;
    float a0 = xi[lane] * d * d;
    float a1 = xi[lane + 64] * d * d;
    int n = cnt[i];
    int s = cursor[i] - n;   // cursor ended at off+cnt after k_fill
    int k = 0;
    for (; k + 1 < n; k += 2) {
        int r0 = eidx[s + k], r1 = eidx[s + k + 1];
        float w0 = dinv[r0] * d, w1 = dinv[r1] * d;
        const float* p0 = x + (size_t)r0 * F1;
        const float* p1 = x + (size_t)r1 * F1;
        a0 = fmaf(p0[lane],      w0, a0);
        a1 = fmaf(p0[lane + 64], w0, a1);
        a0 = fmaf(p1[lane],      w1, a0);
        a1 = fmaf(p1[lane + 64], w1, a1);
    }
    if (k < n) {
        int r0 = eidx[s + k];
        float w0 = dinv[r0] * d;
        const float* p0 = x + (size_t)r0 * F1;
        a0 = fmaf(p0[lane],      w0, a0);
        a1 = fmaf(p0[lane + 64], w0, a1);
    }
    __hip_bfloat16* ag = agg + (size_t)i * F1;
    ag[lane]      = __float2bfloat16(a0);
    ag[lane + 64] = __float2bfloat16(a1);
}

// ---------------- fused GEMM1 + ReLU + GEMM2 ----------------
__global__ __launch_bounds__(256) void k_gemm_fused(
    const __hip_bfloat16* __restrict__ agg, const float* __restrict__ W1,
    const float* __restrict__ b1, const float* __restrict__ W2,
    float* __restrict__ t) {
    __shared__ float a_s[ROWS * F1];   // 8 KB
    __shared__ float h_s[ROWS * F2];   // 16 KB
    const int i0 = blockIdx.x * ROWS;
    const int tid = threadIdx.x;

    for (int o = tid; o < ROWS * F1; o += 256) {
        int r = o >> 7, kk = o & (F1 - 1);
        int i = i0 + r;
        a_s[o] = (i < NN) ? __bfloat162float(agg[(size_t)i * F1 + kk]) : 0.0f;
    }
    __syncthreads();

    {
        const int j = tid;
        float acc[ROWS];
        float bj = b1[j];
#pragma unroll
        for (int r = 0; r < ROWS; ++r) acc[r] = bj;
        for (int k4 = 0; k4 < F1; k4 += 4) {
            float w0 = W1[(k4 + 0) * F2 + j];
            float w1 = W1[(k4 + 1) * F2 + j];
            float w2 = W1[(k4 + 2) * F2 + j];
            float w3 = W1[(k4 + 3) * F2 + j];
#pragma unroll
            for (int r = 0; r < ROWS; ++r) {
                float4 av = *(const float4*)&a_s[r * F1 + k4];
                acc[r] = fmaf(av.x, w0, acc[r]);
                acc[r] = fmaf(av.y, w1, acc[r]);
                acc[r] = fmaf(av.z, w2, acc[r]);
                acc[r] = fmaf(av.w, w3, acc[r]);
            }
        }
#pragma unroll
        for (int r = 0; r < ROWS; ++r) h_s[r * F2 + j] = fmaxf(acc[r], 0.0f);
    }
    __syncthreads();

    for (int o = tid; o < ROWS * F3; o += 256) {
        int r = o / F3, j2 = o - r * F3;
        float s = 0.0f;
        for (int k4 = 0; k4 < F2; k4 += 4) {
            float4 hv = *(const float4*)&h_s[r * F2 + k4];
            s = fmaf(hv.x, W2[(k4 + 0) * F3 + j2], s);
            s = fmaf(hv.y, W2[(k4 + 1) * F3 + j2], s);
            s = fmaf(hv.z, W2[(k4 + 2) * F3 + j2], s);
            s = fmaf(hv.w, W2[(k4 + 3) * F3 + j2], s);
        }
        int i = i0 + r;
        if (i < NN) t[(size_t)i * F3 + j2] = s;
    }
}

// ---------------- layer-2 pull aggregation (40-wide) ----------------
__global__ __launch_bounds__(256) void k_agg2(const int* __restrict__ cursor,
                                              const int* __restrict__ cnt,
                                              const int* __restrict__ eidx,
                                              const float* __restrict__ dinv,
                                              const float* __restrict__ t,
                                              const float* __restrict__ b2,
                                              float* __restrict__ out) {
    int wave = blockIdx.x * 4 + (threadIdx.x >> 6);
    int lane = threadIdx.x & 63;
    if (wave >= NN || lane >= F3) return;
    const int i = wave;
    float d = dinv[i];
    float a = t[(size_t)i * F3 + lane] * d * d + b2[lane];
    int n = cnt[i];
    int s = cursor[i] - n;
    int k = 0;
    for (; k + 1 < n; k += 2) {
        int r0 = eidx[s + k], r1 = eidx[s + k + 1];
        float w0 = dinv[r0] * d, w1 = dinv[r1] * d;
        a = fmaf(t[(size_t)r0 * F3 + lane], w0, a);
        a = fmaf(t[(size_t)r1 * F3 + lane], w1, a);
    }
    if (k < n) {
        int r0 = eidx[s + k];
        a = fmaf(t[(size_t)r0 * F3 + lane], dinv[r0] * d, a);
    }
    out[(size_t)i * F3 + lane] = a;
}

extern "C" void kernel_launch(void* const* d_in, const int* in_sizes, int n_in,
                              void* d_out, int out_size, void* d_ws, size_t ws_size,
                              hipStream_t stream) {
    const float* x  = (const float*)d_in[0];
    const int*   ei = (const int*)d_in[1];
    const float* W1 = (const float*)d_in[2];
    const float* b1 = (const float*)d_in[3];
    const float* W2 = (const float*)d_in[4];
    const float* b2 = (const float*)d_in[5];
    float* out = (float*)d_out;

    const int* row = ei;
    const int* col = ei + EE;

    // ws layout: cnt[N] | cursor[N] | dinv[N] | bsum[512] | eidx[E] | agg bf16[N*128] | t[N*40]
    int* cnt    = (int*)d_ws;
    int* cursor = cnt + NN;
    float* dinv = (float*)(cursor + NN);
    int* bsum   = (int*)(dinv + NN);
    int* eidx   = bsum + 512;
    __hip_bfloat16* agg = (__hip_bfloat16*)(eidx + EE);
    float* t    = (float*)(agg + (size_t)NN * F1);

    k_zero  <<<NB, 256, 0, stream>>>(cnt);
    k_count <<<(EE + 255) / 256, 256, 0, stream>>>(col, cnt);
    k_dinv  <<<NB, 256, 0, stream>>>(cnt, dinv);
    k_scan1 <<<NB, 256, 0, stream>>>(cnt, cursor, bsum);
    k_scan2 <<<1, 512, 0, stream>>>(bsum);
    k_scan3 <<<NB, 256, 0, stream>>>(cursor, bsum);
    k_fill  <<<(EE + 255) / 256, 256, 0, stream>>>(row, col, cursor, eidx);

    k_agg1  <<<(NN + 3) / 4, 256, 0, stream>>>(cursor, cnt, eidx, dinv, x, agg);
    k_gemm_fused<<<(NN + ROWS - 1) / ROWS, 256, 0, stream>>>(agg, W1, b1, W2, t);
    k_agg2  <<<(NN + 3) / 4, 256, 0, stream>>>(cursor, cnt, eidx, dinv, t, b2, out);
}

// Round 3
// 443.553 us; speedup vs baseline: 2.4199x; 1.3622x over previous
//
#include <hip/hip_runtime.h>
#include <hip/hip_bf16.h>

#define NN 100000
#define EE 1200000
#define F1 128
#define F2 256
#define F3 40
#define MROWS 64
#define NB ((NN + 255) / 256)   // 391 scan blocks

typedef __bf16 bf16x8 __attribute__((ext_vector_type(8)));
typedef float  f32x4  __attribute__((ext_vector_type(4)));

// ---------------- CSR build ----------------
__global__ void k_zero(int* __restrict__ cnt) {
    int i = blockIdx.x * blockDim.x + threadIdx.x;
    if (i < NN) cnt[i] = 0;
}

__global__ void k_count(const int* __restrict__ col, int* __restrict__ cnt) {
    int e = blockIdx.x * blockDim.x + threadIdx.x;
    if (e < EE) {
        int c = col[e];
        if ((unsigned)c < (unsigned)NN) atomicAdd(&cnt[c], 1);
    }
}

__global__ void k_dinv(const int* __restrict__ cnt, float* __restrict__ dinv) {
    int i = blockIdx.x * blockDim.x + threadIdx.x;
    if (i < NN) dinv[i] = rsqrtf((float)(cnt[i] + 1));   // +1 self-loop
}

__global__ __launch_bounds__(256) void k_scan1(const int* __restrict__ cnt,
                                               int* __restrict__ cursor,
                                               int* __restrict__ bsum) {
    __shared__ int s[256];
    int g = blockIdx.x * 256 + threadIdx.x;
    int v = (g < NN) ? cnt[g] : 0;
    s[threadIdx.x] = v;
    __syncthreads();
    int acc = v;
    for (int d = 1; d < 256; d <<= 1) {
        int add = (threadIdx.x >= d) ? s[threadIdx.x - d] : 0;
        __syncthreads();
        acc += add;
        s[threadIdx.x] = acc;
        __syncthreads();
    }
    if (g < NN) cursor[g] = acc - v;
    if (threadIdx.x == 255) bsum[blockIdx.x] = acc;
}

__global__ __launch_bounds__(512) void k_scan2(int* __restrict__ bsum) {
    __shared__ int s[512];
    int v = (threadIdx.x < NB) ? bsum[threadIdx.x] : 0;
    s[threadIdx.x] = v;
    __syncthreads();
    int acc = v;
    for (int d = 1; d < 512; d <<= 1) {
        int add = (threadIdx.x >= d) ? s[threadIdx.x - d] : 0;
        __syncthreads();
        acc += add;
        s[threadIdx.x] = acc;
        __syncthreads();
    }
    if (threadIdx.x < NB) bsum[threadIdx.x] = acc - v;
}

__global__ void k_scan3(int* __restrict__ cursor, const int* __restrict__ bsum) {
    int g = blockIdx.x * 256 + threadIdx.x;
    if (g < NN) cursor[g] += bsum[blockIdx.x];
}

__global__ void k_fill(const int* __restrict__ row, const int* __restrict__ col,
                       int* __restrict__ cursor, int* __restrict__ eidx) {
    int e = blockIdx.x * blockDim.x + threadIdx.x;
    if (e < EE) {
        int r = row[e], c = col[e];
        if ((unsigned)r < (unsigned)NN && (unsigned)c < (unsigned)NN) {
            int pos = atomicAdd(&cursor[c], 1);
            eidx[pos] = r;
        }
    }
}

// ---------------- weight packing (one-time, tiny) ----------------
// W1p[k8][col][j] = bf16(W1[k8*8+j][col])   k8<16, col<256, j<8
__global__ void k_prep_w1(const float* __restrict__ W1, __hip_bfloat16* __restrict__ W1p) {
    int idx = blockIdx.x * blockDim.x + threadIdx.x;
    if (idx < F1 * F2) {
        int k = idx / F2, col = idx - (idx / F2) * F2;
        int k8 = k >> 3, j = k & 7;
        W1p[((size_t)(k8 * F2 + col) << 3) + j] = __float2bfloat16(W1[(size_t)k * F2 + col]);
    }
}

// W2p[k8][col][j], col padded 40->48; k8<32, col<48, j<8
__global__ void k_prep_w2(const float* __restrict__ W2, __hip_bfloat16* __restrict__ W2p) {
    int idx = blockIdx.x * blockDim.x + threadIdx.x;
    if (idx < F2 * 48) {
        int k = idx / 48, col = idx - (idx / 48) * 48;
        int k8 = k >> 3, j = k & 7;
        float v = (col < F3) ? W2[(size_t)k * F3 + col] : 0.0f;
        W2p[((size_t)(k8 * 48 + col) << 3) + j] = __float2bfloat16(v);
    }
}

// ---------------- layer-1 pull aggregation (128-wide, bf16 out) ----------------
__global__ __launch_bounds__(256) void k_agg1(const int* __restrict__ cursor,
                                              const int* __restrict__ cnt,
                                              const int* __restrict__ eidx,
                                              const float* __restrict__ dinv,
                                              const float* __restrict__ x,
                                              __hip_bfloat16* __restrict__ agg) {
    int wave = blockIdx.x * 4 + (threadIdx.x >> 6);
    int lane = threadIdx.x & 63;
    if (wave >= NN) return;
    const int i = wave;
    float d = dinv[i];
    const float* xi = x + (size_t)i * F1;
    float a0 = xi[lane] * d * d;
    float a1 = xi[lane + 64] * d * d;
    int n = cnt[i];
    int s = cursor[i] - n;
    int k = 0;
    for (; k + 1 < n; k += 2) {
        int r0 = eidx[s + k], r1 = eidx[s + k + 1];
        float w0 = dinv[r0] * d, w1 = dinv[r1] * d;
        const float* p0 = x + (size_t)r0 * F1;
        const float* p1 = x + (size_t)r1 * F1;
        a0 = fmaf(p0[lane],      w0, a0);
        a1 = fmaf(p0[lane + 64], w0, a1);
        a0 = fmaf(p1[lane],      w1, a0);
        a1 = fmaf(p1[lane + 64], w1, a1);
    }
    if (k < n) {
        int r0 = eidx[s + k];
        float w0 = dinv[r0] * d;
        const float* p0 = x + (size_t)r0 * F1;
        a0 = fmaf(p0[lane],      w0, a0);
        a1 = fmaf(p0[lane + 64], w0, a1);
    }
    __hip_bfloat16* ag = agg + (size_t)i * F1;
    ag[lane]      = __float2bfloat16(a0);
    ag[lane + 64] = __float2bfloat16(a1);
}

// ---------------- fused MFMA GEMM1 + ReLU + GEMM2 ----------------
// Block: 256 thr = 4 waves, 64 rows. Wave w owns rows i0+16w..i0+16w+15.
// GEMM1: A=agg rows (global bf16), B=W1p (L2), acc 16 tiles of 16 cols.
// h=relu(.+b1) -> LDS bf16 (pad 8). GEMM2: A=h_s, B=W2p, 3 col tiles -> t.
__global__ __launch_bounds__(256) void k_gemm_mfma(
    const __hip_bfloat16* __restrict__ agg, const __hip_bfloat16* __restrict__ W1p,
    const float* __restrict__ b1, const __hip_bfloat16* __restrict__ W2p,
    float* __restrict__ t) {
    __shared__ __hip_bfloat16 h_s[MROWS][F2 + 8];   // 33 KB
    const int i0   = blockIdx.x * MROWS;
    const int wave = threadIdx.x >> 6;
    const int lane = threadIdx.x & 63;
    const int m = lane & 15, q = lane >> 4;
    const int rowA = i0 + wave * 16 + m;

    f32x4 acc[16];
#pragma unroll
    for (int c = 0; c < 16; ++c) acc[c] = (f32x4){0.f, 0.f, 0.f, 0.f};

#pragma unroll
    for (int s = 0; s < 4; ++s) {           // K step: k = 32s + 8q + j
        bf16x8 a;
#pragma unroll
        for (int j = 0; j < 8; ++j) a[j] = (__bf16)0.0f;
        if (rowA < NN) a = *(const bf16x8*)(agg + (size_t)rowA * F1 + s * 32 + q * 8);
        const __hip_bfloat16* bp = W1p + ((size_t)(4 * s + q) * F2) * 8;
#pragma unroll
        for (int c = 0; c < 16; ++c) {
            bf16x8 b = *(const bf16x8*)(bp + ((size_t)(c * 16 + m) << 3));
            acc[c] = __builtin_amdgcn_mfma_f32_16x16x32_bf16(a, b, acc[c], 0, 0, 0);
        }
    }

    // bias + relu -> h_s (C layout: col = 16c+m, local row = 16*wave + 4q + r)
#pragma unroll
    for (int c = 0; c < 16; ++c) {
        int col = c * 16 + m;
        float bj = b1[col];
#pragma unroll
        for (int r = 0; r < 4; ++r) {
            int lr = wave * 16 + q * 4 + r;
            h_s[lr][col] = __float2bfloat16(fmaxf(acc[c][r] + bj, 0.0f));
        }
    }
    __syncthreads();

    f32x4 acc2[3];
#pragma unroll
    for (int c = 0; c < 3; ++c) acc2[c] = (f32x4){0.f, 0.f, 0.f, 0.f};

#pragma unroll
    for (int s = 0; s < 8; ++s) {           // K step over 256
        bf16x8 a = *(const bf16x8*)(&h_s[wave * 16 + m][s * 32 + q * 8]);
        const __hip_bfloat16* bp = W2p + ((size_t)(4 * s + q) * 48) * 8;
#pragma unroll
        for (int c = 0; c < 3; ++c) {
            bf16x8 b = *(const bf16x8*)(bp + ((size_t)(c * 16 + m) << 3));
            acc2[c] = __builtin_amdgcn_mfma_f32_16x16x32_bf16(a, b, acc2[c], 0, 0, 0);
        }
    }

#pragma unroll
    for (int c = 0; c < 3; ++c) {
        int col = c * 16 + m;
        if (col < F3) {
#pragma unroll
            for (int r = 0; r < 4; ++r) {
                int grow = i0 + wave * 16 + q * 4 + r;
                if (grow < NN) t[(size_t)grow * F3 + col] = acc2[c][r];
            }
        }
    }
}

// ---------------- layer-2 pull aggregation (40-wide) ----------------
__global__ __launch_bounds__(256) void k_agg2(const int* __restrict__ cursor,
                                              const int* __restrict__ cnt,
                                              const int* __restrict__ eidx,
                                              const float* __restrict__ dinv,
                                              const float* __restrict__ t,
                                              const float* __restrict__ b2,
                                              float* __restrict__ out) {
    int wave = blockIdx.x * 4 + (threadIdx.x >> 6);
    int lane = threadIdx.x & 63;
    if (wave >= NN || lane >= F3) return;
    const int i = wave;
    float d = dinv[i];
    float a = t[(size_t)i * F3 + lane] * d * d + b2[lane];
    int n = cnt[i];
    int s = cursor[i] - n;
    int k = 0;
    for (; k + 1 < n; k += 2) {
        int r0 = eidx[s + k], r1 = eidx[s + k + 1];
        float w0 = dinv[r0] * d, w1 = dinv[r1] * d;
        a = fmaf(t[(size_t)r0 * F3 + lane], w0, a);
        a = fmaf(t[(size_t)r1 * F3 + lane], w1, a);
    }
    if (k < n) {
        int r0 = eidx[s + k];
        a = fmaf(t[(size_t)r0 * F3 + lane], dinv[r0] * d, a);
    }
    out[(size_t)i * F3 + lane] = a;
}

extern "C" void kernel_launch(void* const* d_in, const int* in_sizes, int n_in,
                              void* d_out, int out_size, void* d_ws, size_t ws_size,
                              hipStream_t stream) {
    const float* x  = (const float*)d_in[0];
    const int*   ei = (const int*)d_in[1];
    const float* W1 = (const float*)d_in[2];
    const float* b1 = (const float*)d_in[3];
    const float* W2 = (const float*)d_in[4];
    const float* b2 = (const float*)d_in[5];
    float* out = (float*)d_out;

    const int* row = ei;
    const int* col = ei + EE;

    // ws: cnt[N] | cursor[N] | dinv[N] | bsum[512] | eidx[E] | agg bf16[N*128]
    //     | t[N*40] | W1p bf16[32768] | W2p bf16[12288]
    int* cnt    = (int*)d_ws;
    int* cursor = cnt + NN;
    float* dinv = (float*)(cursor + NN);
    int* bsum   = (int*)(dinv + NN);
    int* eidx   = bsum + 512;
    __hip_bfloat16* agg = (__hip_bfloat16*)(eidx + EE);
    float* t    = (float*)(agg + (size_t)NN * F1);
    __hip_bfloat16* W1p = (__hip_bfloat16*)(t + (size_t)NN * F3);
    __hip_bfloat16* W2p = W1p + (size_t)F1 * F2;

    k_zero  <<<NB, 256, 0, stream>>>(cnt);
    k_count <<<(EE + 255) / 256, 256, 0, stream>>>(col, cnt);
    k_dinv  <<<NB, 256, 0, stream>>>(cnt, dinv);
    k_scan1 <<<NB, 256, 0, stream>>>(cnt, cursor, bsum);
    k_scan2 <<<1, 512, 0, stream>>>(bsum);
    k_scan3 <<<NB, 256, 0, stream>>>(cursor, bsum);
    k_fill  <<<(EE + 255) / 256, 256, 0, stream>>>(row, col, cursor, eidx);

    k_prep_w1<<<(F1 * F2 + 255) / 256, 256, 0, stream>>>(W1, W1p);
    k_prep_w2<<<(F2 * 48 + 255) / 256, 256, 0, stream>>>(W2, W2p);

    k_agg1  <<<(NN + 3) / 4, 256, 0, stream>>>(cursor, cnt, eidx, dinv, x, agg);
    k_gemm_mfma<<<(NN + MROWS - 1) / MROWS, 256, 0, stream>>>(agg, W1p, b1, W2p, t);
    k_agg2  <<<(NN + 3) / 4, 256, 0, stream>>>(cursor, cnt, eidx, dinv, t, b2, out);
}

// Round 4
// 405.012 us; speedup vs baseline: 2.6502x; 1.0952x over previous
//
#include <hip/hip_runtime.h>
#include <hip/hip_bf16.h>

#define NN 100000
#define EE 1200000
#define F1 128
#define F2 256
#define F3 40
#define MROWS 64
#define NB ((NN + 255) / 256)   // 391 scan blocks

typedef __bf16 bf16x8 __attribute__((ext_vector_type(8)));
typedef float  f32x4  __attribute__((ext_vector_type(4)));

__device__ __forceinline__ unsigned short f2bf(float f) {   // RNE bf16
    unsigned u = __float_as_uint(f);
    return (unsigned short)((u + 0x7fffu + ((u >> 16) & 1u)) >> 16);
}
__device__ __forceinline__ float bflo(unsigned v) { return __uint_as_float(v << 16); }
__device__ __forceinline__ float bfhi(unsigned v) { return __uint_as_float(v & 0xffff0000u); }

// ---------------- CSR build ----------------
__global__ void k_count(const int* __restrict__ col, int* __restrict__ cnt) {
    int e = blockIdx.x * blockDim.x + threadIdx.x;
    if (e < EE) {
        int c = col[e];
        if ((unsigned)c < (unsigned)NN) atomicAdd(&cnt[c], 1);
    }
}

// block scan of cnt -> cursor (excl within block), block totals -> bsum; also dinv
__global__ __launch_bounds__(256) void k_scan1(const int* __restrict__ cnt,
                                               int* __restrict__ cursor,
                                               int* __restrict__ bsum,
                                               float* __restrict__ dinv) {
    __shared__ int s[256];
    int g = blockIdx.x * 256 + threadIdx.x;
    int v = (g < NN) ? cnt[g] : 0;
    s[threadIdx.x] = v;
    __syncthreads();
    int acc = v;
    for (int d = 1; d < 256; d <<= 1) {
        int add = (threadIdx.x >= d) ? s[threadIdx.x - d] : 0;
        __syncthreads();
        acc += add;
        s[threadIdx.x] = acc;
        __syncthreads();
    }
    if (g < NN) {
        cursor[g] = acc - v;
        dinv[g] = rsqrtf((float)(v + 1));   // +1 self-loop
    }
    if (threadIdx.x == 255) bsum[blockIdx.x] = acc;
}

__global__ __launch_bounds__(512) void k_scan2(int* __restrict__ bsum) {
    __shared__ int s[512];
    int v = (threadIdx.x < NB) ? bsum[threadIdx.x] : 0;
    s[threadIdx.x] = v;
    __syncthreads();
    int acc = v;
    for (int d = 1; d < 512; d <<= 1) {
        int add = (threadIdx.x >= d) ? s[threadIdx.x - d] : 0;
        __syncthreads();
        acc += add;
        s[threadIdx.x] = acc;
        __syncthreads();
    }
    if (threadIdx.x < NB) bsum[threadIdx.x] = acc - v;
}

__global__ void k_scan3(int* __restrict__ cursor, const int* __restrict__ bsum) {
    int g = blockIdx.x * 256 + threadIdx.x;
    if (g < NN) cursor[g] += bsum[blockIdx.x];
}

__global__ void k_fill(const int* __restrict__ row, const int* __restrict__ col,
                       int* __restrict__ cursor, int* __restrict__ eidx) {
    int e = blockIdx.x * blockDim.x + threadIdx.x;
    if (e < EE) {
        int r = row[e], c = col[e];
        if ((unsigned)r < (unsigned)NN && (unsigned)c < (unsigned)NN) {
            int pos = atomicAdd(&cursor[c], 1);
            eidx[pos] = r;
        }
    }
}

// ---------------- prescaled bf16 x:  xh[i] = bf16(x[i] * dinv[i]) ----------------
__global__ void k_prep_x(const float2* __restrict__ x, const float* __restrict__ dinv,
                         unsigned* __restrict__ xh) {
    int idx = blockIdx.x * blockDim.x + threadIdx.x;   // NN*64 dword-pairs
    if (idx < NN * 64) {
        float d = dinv[idx >> 6];
        float2 v = x[idx];
        xh[idx] = (unsigned)f2bf(v.x * d) | ((unsigned)f2bf(v.y * d) << 16);
    }
}

// ---------------- weight packing (one-time, tiny) ----------------
// W1p[k8][col][j] = bf16(W1[k8*8+j][col]); W2p[k8][col][j] col padded 40->48
__global__ void k_prep_w(const float* __restrict__ W1, const float* __restrict__ W2,
                         __hip_bfloat16* __restrict__ W1p, __hip_bfloat16* __restrict__ W2p) {
    int idx = blockIdx.x * blockDim.x + threadIdx.x;
    if (idx < F1 * F2) {
        int k = idx / F2, col = idx - (idx / F2) * F2;
        int k8 = k >> 3, j = k & 7;
        W1p[((size_t)(k8 * F2 + col) << 3) + j] = __float2bfloat16(W1[(size_t)k * F2 + col]);
    } else if (idx < F1 * F2 + F2 * 48) {
        int i2 = idx - F1 * F2;
        int k = i2 / 48, col = i2 - (i2 / 48) * 48;
        int k8 = k >> 3, j = k & 7;
        float v = (col < F3) ? W2[(size_t)k * F3 + col] : 0.0f;
        W2p[((size_t)(k8 * 48 + col) << 3) + j] = __float2bfloat16(v);
    }
}

// ---------------- layer-1 pull aggregation (bf16 gather, 256 B/edge) ----------------
// one wave per node; lane handles features 2*lane, 2*lane+1
__global__ __launch_bounds__(256) void k_agg1(const int* __restrict__ cursor,
                                              const int* __restrict__ cnt,
                                              const int* __restrict__ eidx,
                                              const float* __restrict__ dinv,
                                              const unsigned* __restrict__ xh,
                                              unsigned* __restrict__ agg) {
    int node = blockIdx.x * 4 + (threadIdx.x >> 6);
    int lane = threadIdx.x & 63;
    if (node >= NN) return;
    unsigned vs = xh[((size_t)node << 6) + lane];
    float a0 = bflo(vs), a1 = bfhi(vs);
    int n = cnt[node];
    int s = cursor[node] - n;   // cursor ended at off+cnt after k_fill
    int k = 0;
    for (; k + 3 < n; k += 4) {
        int r0 = eidx[s + k], r1 = eidx[s + k + 1];
        int r2 = eidx[s + k + 2], r3 = eidx[s + k + 3];
        unsigned v0 = xh[((size_t)r0 << 6) + lane];
        unsigned v1 = xh[((size_t)r1 << 6) + lane];
        unsigned v2 = xh[((size_t)r2 << 6) + lane];
        unsigned v3 = xh[((size_t)r3 << 6) + lane];
        a0 += bflo(v0); a1 += bfhi(v0);
        a0 += bflo(v1); a1 += bfhi(v1);
        a0 += bflo(v2); a1 += bfhi(v2);
        a0 += bflo(v3); a1 += bfhi(v3);
    }
    for (; k < n; ++k) {
        unsigned v0 = xh[((size_t)eidx[s + k] << 6) + lane];
        a0 += bflo(v0); a1 += bfhi(v0);
    }
    float d = dinv[node];
    a0 *= d; a1 *= d;
    agg[((size_t)node << 6) + lane] = (unsigned)f2bf(a0) | ((unsigned)f2bf(a1) << 16);
}

// ---------------- fused MFMA GEMM1 + ReLU + GEMM2, store tg = (h@W2)*dinv bf16 ----
__global__ __launch_bounds__(256) void k_gemm_mfma(
    const __hip_bfloat16* __restrict__ agg, const __hip_bfloat16* __restrict__ W1p,
    const float* __restrict__ b1, const __hip_bfloat16* __restrict__ W2p,
    const float* __restrict__ dinv, unsigned short* __restrict__ tg) {
    __shared__ __hip_bfloat16 h_s[MROWS][F2 + 8];   // 33 KB
    const int i0   = blockIdx.x * MROWS;
    const int wave = threadIdx.x >> 6;
    const int lane = threadIdx.x & 63;
    const int m = lane & 15, q = lane >> 4;
    const int rowA = i0 + wave * 16 + m;

    f32x4 acc[16];
#pragma unroll
    for (int c = 0; c < 16; ++c) acc[c] = (f32x4){0.f, 0.f, 0.f, 0.f};

#pragma unroll
    for (int s = 0; s < 4; ++s) {           // k = 32s + 8q + j
        bf16x8 a;
#pragma unroll
        for (int j = 0; j < 8; ++j) a[j] = (__bf16)0.0f;
        if (rowA < NN) a = *(const bf16x8*)(agg + (size_t)rowA * F1 + s * 32 + q * 8);
        const __hip_bfloat16* bp = W1p + ((size_t)(4 * s + q) * F2) * 8;
#pragma unroll
        for (int c = 0; c < 16; ++c) {
            bf16x8 b = *(const bf16x8*)(bp + ((size_t)(c * 16 + m) << 3));
            acc[c] = __builtin_amdgcn_mfma_f32_16x16x32_bf16(a, b, acc[c], 0, 0, 0);
        }
    }

#pragma unroll
    for (int c = 0; c < 16; ++c) {
        int col = c * 16 + m;
        float bj = b1[col];
#pragma unroll
        for (int r = 0; r < 4; ++r) {
            int lr = wave * 16 + q * 4 + r;
            h_s[lr][col] = __float2bfloat16(fmaxf(acc[c][r] + bj, 0.0f));
        }
    }
    __syncthreads();

    f32x4 acc2[3];
#pragma unroll
    for (int c = 0; c < 3; ++c) acc2[c] = (f32x4){0.f, 0.f, 0.f, 0.f};

#pragma unroll
    for (int s = 0; s < 8; ++s) {
        bf16x8 a = *(const bf16x8*)(&h_s[wave * 16 + m][s * 32 + q * 8]);
        const __hip_bfloat16* bp = W2p + ((size_t)(4 * s + q) * 48) * 8;
#pragma unroll
        for (int c = 0; c < 3; ++c) {
            bf16x8 b = *(const bf16x8*)(bp + ((size_t)(c * 16 + m) << 3));
            acc2[c] = __builtin_amdgcn_mfma_f32_16x16x32_bf16(a, b, acc2[c], 0, 0, 0);
        }
    }

#pragma unroll
    for (int c = 0; c < 3; ++c) {
        int col = c * 16 + m;
        if (col < F3) {
#pragma unroll
            for (int r = 0; r < 4; ++r) {
                int grow = i0 + wave * 16 + q * 4 + r;
                if (grow < NN) tg[(size_t)grow * F3 + col] = f2bf(acc2[c][r] * dinv[grow]);
            }
        }
    }
}

// ---------------- layer-2 pull aggregation (bf16 gather, 80 B/edge) ----------------
__global__ __launch_bounds__(256) void k_agg2(const int* __restrict__ cursor,
                                              const int* __restrict__ cnt,
                                              const int* __restrict__ eidx,
                                              const float* __restrict__ dinv,
                                              const unsigned short* __restrict__ tg,
                                              const float* __restrict__ b2,
                                              float* __restrict__ out) {
    int node = blockIdx.x * 4 + (threadIdx.x >> 6);
    int lane = threadIdx.x & 63;
    if (node >= NN || lane >= F3) return;
    float a = __uint_as_float((unsigned)tg[(size_t)node * F3 + lane] << 16);
    int n = cnt[node];
    int s = cursor[node] - n;
    int k = 0;
    for (; k + 3 < n; k += 4) {
        int r0 = eidx[s + k], r1 = eidx[s + k + 1];
        int r2 = eidx[s + k + 2], r3 = eidx[s + k + 3];
        float v0 = __uint_as_float((unsigned)tg[(size_t)r0 * F3 + lane] << 16);
        float v1 = __uint_as_float((unsigned)tg[(size_t)r1 * F3 + lane] << 16);
        float v2 = __uint_as_float((unsigned)tg[(size_t)r2 * F3 + lane] << 16);
        float v3 = __uint_as_float((unsigned)tg[(size_t)r3 * F3 + lane] << 16);
        a += v0 + v1 + v2 + v3;
    }
    for (; k < n; ++k)
        a += __uint_as_float((unsigned)tg[(size_t)eidx[s + k] * F3 + lane] << 16);
    out[(size_t)node * F3 + lane] = dinv[node] * a + b2[lane];
}

extern "C" void kernel_launch(void* const* d_in, const int* in_sizes, int n_in,
                              void* d_out, int out_size, void* d_ws, size_t ws_size,
                              hipStream_t stream) {
    const float* x  = (const float*)d_in[0];
    const int*   ei = (const int*)d_in[1];
    const float* W1 = (const float*)d_in[2];
    const float* b1 = (const float*)d_in[3];
    const float* W2 = (const float*)d_in[4];
    const float* b2 = (const float*)d_in[5];
    float* out = (float*)d_out;

    const int* row = ei;
    const int* col = ei + EE;

    // ws: cnt[N] | cursor[N] | dinv[N] | bsum[512] | eidx[E] | xh[N*64 u32]
    //     | agg[N*64 u32] | tg[N*40 bf16] | W1p[32768 bf16] | W2p[12288 bf16]  ~65.3 MB
    int* cnt    = (int*)d_ws;
    int* cursor = cnt + NN;
    float* dinv = (float*)(cursor + NN);
    int* bsum   = (int*)(dinv + NN);
    int* eidx   = bsum + 512;
    unsigned* xh  = (unsigned*)(eidx + EE);
    unsigned* agg = xh + (size_t)NN * 64;
    unsigned short* tg = (unsigned short*)(agg + (size_t)NN * 64);
    __hip_bfloat16* W1p = (__hip_bfloat16*)(tg + (size_t)NN * F3);
    __hip_bfloat16* W2p = W1p + (size_t)F1 * F2;

    hipMemsetAsync(cnt, 0, NN * sizeof(int), stream);
    k_count <<<(EE + 255) / 256, 256, 0, stream>>>(col, cnt);
    k_scan1 <<<NB, 256, 0, stream>>>(cnt, cursor, bsum, dinv);
    k_scan2 <<<1, 512, 0, stream>>>(bsum);
    k_scan3 <<<NB, 256, 0, stream>>>(cursor, bsum);
    k_fill  <<<(EE + 255) / 256, 256, 0, stream>>>(row, col, cursor, eidx);

    k_prep_x<<<(NN * 64 + 255) / 256, 256, 0, stream>>>((const float2*)x, dinv, xh);
    k_prep_w<<<(F1 * F2 + F2 * 48 + 255) / 256, 256, 0, stream>>>(W1, W2, W1p, W2p);

    k_agg1  <<<(NN + 3) / 4, 256, 0, stream>>>(cursor, cnt, eidx, dinv, xh, agg);
    k_gemm_mfma<<<(NN + MROWS - 1) / MROWS, 256, 0, stream>>>(
        (const __hip_bfloat16*)agg, W1p, b1, W2p, dinv, tg);
    k_agg2  <<<(NN + 3) / 4, 256, 0, stream>>>(cursor, cnt, eidx, dinv, tg, b2, out);
}